// Round 18
// baseline (18.098 us; speedup 1.0000x reference)
//
#include <hip/hip_runtime.h>

#define BB 8
#define HH 64
#define WW 2048
#define HW (HH * WW)
#define NC 20
#define NXB 16

// R18: 2 px/thread, row-streamed, targeting 32 waves/CU (8 waves/SIMD).
// R17 confirmed R14's 12.4us is stable and stall-bound (~25% VALU issue,
// 4 waves/SIMD). Only remaining lever: TLP. 2 px/thread doubles waves to
// 8192 = exactly 32/CU -- requires VGPR<=64, so the kernel is STRUCTURED
// for a small live set (R5 scar: don't cap a big live set, shrink it):
//  - 10-col window, only 2 rows live (crow + streamed krow), runtime ky loop
//  - ad[6] |diff| shared across the 2 px; edge conv-x-mask via ad[s]*=mxm[s]
//    (exact: |d|*1.0==|d|, *0.0==+0, fmaf(w,+0,acc)==acc) -- R13-proven
//  - loads: 5 aligned float2 per row, clamped base; <=2 divergent fixup
//    lanes/wave (R14's balanced-edge pattern, u/o in {2,4})
// Gate (exact, monotone, R11-R17-proven): reference fma chain prefix for tap
// row jyS=max(0,2-gy); prefix>1 => final>1 => all neighbors vote NC => own
// label. Gate-fail waves (P~1e-5) run R12's HW-validated slow path.
// Tripwires: WRITE_SIZE must stay ~4096KB (no scratch); if dur >= 13us the
// VGPR tier was missed -> revert to R14/R17 next round.

__device__ __forceinline__ float gdepth(const float* __restrict__ Db, int y, int x) {
    // exact reference unfold zero-pad
    return ((unsigned)y < (unsigned)HH && (unsigned)x < (unsigned)WW)
               ? Db[y * WW + x] : 0.0f;
}

// Load 10 cols of image row ry from clamped 8B-aligned base cb into w[10];
// zero if row OOB (exact unfold pad). Per-lane realign for edge lanes:
// u (left-clamped shift) and o (right-clamped shift), both in {0,2,4}.
__device__ __forceinline__ void load_row(const float* __restrict__ Db,
                                         int ry, int cb, int u, int o,
                                         float w[10]) {
    if ((unsigned)ry < (unsigned)HH) {          // wave-uniform branch
        const float2* rp = reinterpret_cast<const float2*>(Db + ry * WW + cb);
        const float2 v0 = rp[0], v1 = rp[1], v2 = rp[2], v3 = rp[3], v4 = rp[4];
        w[0] = v0.x; w[1] = v0.y; w[2] = v1.x; w[3] = v1.y; w[4] = v2.x;
        w[5] = v2.y; w[6] = v3.x; w[7] = v3.y; w[8] = v4.x; w[9] = v4.y;
        // divergent fixup, <=2 active lanes/wave, static indices only
        if (u >= 2) {
#pragma unroll
            for (int c = 9; c >= 2; --c) w[c] = w[c - 2];
            w[0] = 0.0f; w[1] = 0.0f;
        }
        if (u >= 4) {
#pragma unroll
            for (int c = 9; c >= 2; --c) w[c] = w[c - 2];
            w[0] = 0.0f; w[1] = 0.0f;
        }
        if (o >= 2) {
#pragma unroll
            for (int c = 0; c <= 7; ++c) w[c] = w[c + 2];
            w[8] = 0.0f; w[9] = 0.0f;
        }
        if (o >= 4) {
#pragma unroll
            for (int c = 0; c <= 7; ++c) w[c] = w[c + 2];
            w[8] = 0.0f; w[9] = 0.0f;
        }
    } else {
#pragma unroll
        for (int c = 0; c < 10; ++c) w[c] = 0.0f;
    }
}

template <bool EDGE>
__device__ __forceinline__ float gate_min2(const float* __restrict__ Db,
                                           const float crow[10],
                                           int rtop, int cb, int u, int o,
                                           const float wjs[5],
                                           const float mxm[6]) {
    float mn = 3.4e38f;
    // runtime ky loop: keeps only crow + one krow live (bounded register set)
#pragma clang loop unroll(disable)
    for (int ky = 0; ky < 5; ++ky) {
        float krow[10];
        if (ky == 2) {                           // wave-uniform
#pragma unroll
            for (int c = 0; c < 10; ++c) krow[c] = crow[c];
        } else {
            load_row(Db, rtop + ky, cb, u, o, krow);
        }
#pragma unroll
        for (int kx = 0; kx < 5; ++kx) {
            if (kx == 2) {
                if (ky == 2) continue;           // self: dist exactly +0.0
            }
            // |diff| shared by both pixels (s = p + jx); x-mask on edge
            // blocks multiplies by exact 1.0/0.0 (fmaf(w,+0,acc)==acc)
            float ad[6];
#pragma unroll
            for (int s = 0; s < 6; ++s) {
                const float d = fabsf(krow[s + kx] - crow[s + 2]);
                ad[s] = EDGE ? d * mxm[s] : d;
            }
#pragma unroll
            for (int p = 0; p < 2; ++p) {
                float d = 0.0f;                  // ref chain: jx ascending
#pragma unroll
                for (int jx = 0; jx < 5; ++jx)
                    d = fmaf(wjs[jx], ad[p + jx], d);
                mn = fminf(mn, d);               // exact, order-free
            }
        }
    }
    return mn;
}

__global__ __launch_bounds__(256, 8) void knn_refine(
    const float* __restrict__ depth,
    const int*   __restrict__ label,
    const float* __restrict__ wker,
    int*         __restrict__ out)
{
    const int t    = threadIdx.x;
    const int lane = t & 63;
    const int b    = blockIdx.z;
    const int gy   = blockIdx.y * 4 + (t >> 6);        // wave-uniform
    const int gx0  = blockIdx.x * 128 + lane * 2;      // 2 px: gx0, gx0+1

    const float* Db = depth + (size_t)b * HW;
    const int*   Lb = label + (size_t)b * HW;

    // own labels (k=12 dist==+0.0 is always the first top-k pick:
    // strict-< scan, ties -> lower k = lax.top_k)
    const int2 lab2 = *reinterpret_cast<const int2*>(Lb + gy * WW + gx0);

    const int  jyS  = (gy < 2) ? (2 - gy) : 0;   // first unmasked tap row
    const int  rtop = gy + jyS - 4;              // window top image row
    const bool edge = (blockIdx.x == 0) | (blockIdx.x == NXB - 1);

    // gate-row weights
    float wjs[5];
#pragma unroll
    for (int jx = 0; jx < 5; ++jx) wjs[jx] = wker[jyS * 5 + jx];

    // clamped 8B-aligned base; u/o in {0,2,4}, <=2 special lanes per edge wave
    int base = gx0 - 4;
    int u = 0, o = 0;
    if (base < 0)            { u = -base;            base = 0; }
    else if (base > WW - 10) { o = base - (WW - 10); base = WW - 10; }

    // anchor-col masks (edge blocks only): anchor x = gx0 + s - 2
    float mxm[6];
    if (edge) {
#pragma unroll
        for (int s = 0; s < 6; ++s)
            mxm[s] = ((unsigned)(gx0 + s - 2) < (unsigned)WW) ? 1.0f : 0.0f;
    }

    // center row (anchor row rtop+2 is always in-image)
    float crow[10];
    load_row(Db, rtop + 2, base, u, o, crow);

    const float mn = edge ? gate_min2<true>(Db, crow, rtop, base, u, o, wjs, mxm)
                          : gate_min2<false>(Db, crow, rtop, base, u, o, wjs, mxm);

    if (__all(mn > 1.0f)) {                 // prefix>1 => final>1 (monotone)
        *reinterpret_cast<int2*>(out + (size_t)b * HW + gy * WW + gx0) = lab2;
        return;
    }

    // ---- slow path (rare, wave-uniform): R12's validated full recompute ----
#pragma clang loop unroll(disable)
    for (int p = 0; p < 2; ++p) {
        const int gx = gx0 + p;

        float mxp[5];
#pragma unroll
        for (int d = 0; d < 5; ++d)
            mxp[d] = ((unsigned)(gx + d - 2) < (unsigned)WW) ? 1.0f : 0.0f;

        float dist[25];
#pragma unroll
        for (int k = 0; k < 25; ++k) dist[k] = 0.0f;

#pragma clang loop unroll(disable)
        for (int jy = 0; jy < 5; ++jy) {
            float row[5][9];                // statically indexed only
#pragma unroll
            for (int r = 0; r < 5; ++r)
#pragma unroll
                for (int c = 0; c < 9; ++c)
                    row[r][c] = gdepth(Db, gy + jy + r - 4, gx + c - 4);
            const float myy =
                ((unsigned)(gy + jy - 2) < (unsigned)HH) ? 1.0f : 0.0f;
#pragma unroll
            for (int jx = 0; jx < 5; ++jx) {
                const float wj = myy * mxp[jx] * wker[jy * 5 + jx];
                const float Dq = row[2][jx + 2];
#pragma unroll
                for (int k = 0; k < 25; ++k) {
                    if (k == 12) continue;
                    const int ky = k / 5, kx = k % 5;
                    const int nlin = ky * 9 + jx + kx, alin = 18 + jx + 2;
                    const float diff = (nlin > alin) ? (row[ky][jx + kx] - Dq)
                                                     : (Dq - row[ky][jx + kx]);
                    dist[k] = fmaf(wj, fabsf(diff), dist[k]);
                }
            }
        }

        int labs[5];
        labs[0] = Lb[gy * WW + gx];
#pragma unroll
        for (int r = 1; r < 5; ++r) {
            float best = 3.4e38f;
            int bi = 0;
#pragma unroll
            for (int k = 0; k < 25; ++k) {
                if (k == 12) continue;
                if (dist[k] < best) { best = dist[k]; bi = k; }
            }
            int ky = (bi * 205) >> 10, kx = bi - ky * 5;   // bi/5, bi%5
            int ny = gy + ky - 2, nx = gx + kx - 2;
            // label unfold zero-pad: OOB neighbor label = 0
            int lv = ((unsigned)ny < (unsigned)HH && (unsigned)nx < (unsigned)WW)
                         ? Lb[ny * WW + nx] : 0;
            labs[r] = (best > 1.0f) ? NC : lv;
            if (r < 4) {
#pragma unroll
                for (int k = 0; k < 25; ++k) {
                    if (k == 12) continue;
                    if (k == bi) dist[k] = 3.4e38f;
                }
            }
        }

        int bestLab = 0, bestCnt = 0;
#pragma unroll
        for (int i = 0; i < 5; ++i) {
            const int li = labs[i];
            int c = 0;
#pragma unroll
            for (int j = 0; j < 5; ++j) c += (labs[j] == li) ? 1 : 0;
            if (li < NC && (c > bestCnt || (c == bestCnt && li < bestLab))) {
                bestCnt = c;
                bestLab = li;
            }
        }
        out[(size_t)b * HW + (size_t)gy * WW + gx] = bestLab;
    }
}

extern "C" void kernel_launch(void* const* d_in, const int* in_sizes, int n_in,
                              void* d_out, int out_size, void* d_ws, size_t ws_size,
                              hipStream_t stream) {
    const float* depth = (const float*)d_in[0];
    const int*   label = (const int*)d_in[1];
    const float* wker  = (const float*)d_in[2];
    int*         out   = (int*)d_out;

    knn_refine<<<dim3(NXB, 16, BB), dim3(256), 0, stream>>>(depth, label, wker, out);
}